// Round 3
// baseline (99.692 us; speedup 1.0000x reference)
//
#include <hip/hip_runtime.h>
#include <math.h>

// Problem constants (x: (5,1,256,64,64) f32)
constexpr int NIMG = 5;
constexpr int CCH  = 256;   // channels (both c and d)
constexpr int HWP  = 4096;  // H*W
constexpr int PT   = CCH * HWP;  // pixels per image = 1048576

// GEMM tiling
constexpr int BD = 64;    // d-tile
constexpr int BP = 64;    // p-tile
constexpr int BK = 32;    // K-step

// Async global->LDS, 16B per lane. Dest must be wave-uniform base; HW adds lane*16.
__device__ __forceinline__ void gload16(const float* g, float* l) {
    __builtin_amdgcn_global_load_lds(
        (const __attribute__((address_space(1))) unsigned int*)g,
        (__attribute__((address_space(3))) unsigned int*)l, 16, 0, 0);
}

// -----------------------------------------------------------------------------
// Kernel 1: per-image channel-mixing GEMM producing
//   u[n,d,p] = x[n,d,p] - sum_c x[n,c,p]*(W1+W2)[c,d] - b[d]
//   v[n,d,p] = sum_c x[n,c,p]*W2[c,d]
// 64d x 64p block, BK=32, 256 threads, 4x4 micro-tile, dual accumulator.
// LDS 24 KB -> 6 blocks/CU residency. Staging via global_load_lds width=16.
// (w1+w2) add moved into inner loop: identical fp32 value/chain as before
// -> u,v bit-identical to the R1 passing version.
// -----------------------------------------------------------------------------
__global__ __launch_bounds__(256) void uv_gemm(
    const float* __restrict__ x, const float* __restrict__ w,
    const float* __restrict__ bias, float* __restrict__ u, float* __restrict__ v)
{
    const int t  = threadIdx.x;
    const int tp = t & 15;   // p-group: owns cols tp*4..+3
    const int td = t >> 4;   // d-group: owns rows td*4..+3
    const int p0 = blockIdx.x * BP;
    const int d0 = blockIdx.y * BD;
    const int n  = blockIdx.z;
    const float* xn = x + (size_t)n * PT;

    __shared__ float xs [BK][BP];  // 8 KB
    __shared__ float w1s[BK][BD];  // 8 KB
    __shared__ float w2s[BK][BD];  // 8 KB

    float acc_s[4][4] = {};  // sum_c x*(W1+W2)
    float acc_2[4][4] = {};  // sum_c x*W2

    const int wv = t >> 6;        // wave 0..3
    const int ln = t & 63;
    const int sr = ln >> 4;       // sub-row within 4-row chunk
    const int sc = (ln & 15) * 4; // col within row

    for (int c0 = 0; c0 < CCH; c0 += BK) {
        // Stage 3 x [32][64] tiles. 8 chunks of 4 rows each per tile;
        // wave wv handles chunks wv and wv+4. LDS dest linear (1KB/chunk).
        #pragma unroll
        for (int k = 0; k < 2; ++k) {
            const int r0 = (wv + k * 4) * 4;  // chunk base row
            const int r  = r0 + sr;
            gload16(&xn[(size_t)(c0 + r) * HWP + p0 + sc], &xs[r0][0]);
            gload16(&w [(size_t)(c0 + r) * CCH + d0 + sc], &w1s[r0][0]);
            gload16(&w [(size_t)(256 + c0 + r) * CCH + d0 + sc], &w2s[r0][0]);
        }
        __syncthreads();  // compiler drains vmcnt before barrier

        #pragma unroll 8
        for (int cc = 0; cc < BK; ++cc) {
            const float4 xv  = *reinterpret_cast<const float4*>(&xs [cc][tp * 4]);
            const float4 w1v = *reinterpret_cast<const float4*>(&w1s[cc][td * 4]);
            const float4 w2v = *reinterpret_cast<const float4*>(&w2s[cc][td * 4]);
            const float xa [4] = {xv.x, xv.y, xv.z, xv.w};
            const float w2a[4] = {w2v.x, w2v.y, w2v.z, w2v.w};
            const float wsa[4] = {w1v.x + w2v.x, w1v.y + w2v.y,
                                  w1v.z + w2v.z, w1v.w + w2v.w};
            #pragma unroll
            for (int i = 0; i < 4; ++i) {
                #pragma unroll
                for (int j = 0; j < 4; ++j) {
                    acc_s[i][j] = fmaf(wsa[i], xa[j], acc_s[i][j]);
                    acc_2[i][j] = fmaf(w2a[i], xa[j], acc_2[i][j]);
                }
            }
        }
        __syncthreads();
    }

    // Epilogue: u = x - acc_s - b[d], v = acc_2
    #pragma unroll
    for (int i = 0; i < 4; ++i) {
        const int d = d0 + td * 4 + i;
        const float bd = bias[d];
        const size_t base = (size_t)d * HWP + p0 + tp * 4;
        const float4 xv = *reinterpret_cast<const float4*>(&xn[base]);
        float4 uo, vo;
        uo.x = xv.x - acc_s[i][0] - bd;
        uo.y = xv.y - acc_s[i][1] - bd;
        uo.z = xv.z - acc_s[i][2] - bd;
        uo.w = xv.w - acc_s[i][3] - bd;
        vo.x = acc_2[i][0]; vo.y = acc_2[i][1];
        vo.z = acc_2[i][2]; vo.w = acc_2[i][3];
        *reinterpret_cast<float4*>(&u[(size_t)n * PT + base]) = uo;
        *reinterpret_cast<float4*>(&v[(size_t)n * PT + base]) = vo;
    }
}

// -----------------------------------------------------------------------------
// Kernel 2: per-pixel 5x5 edge matrix e[i][j] = |u[j]-v[i]|, row-norm over j,
// threshold e/max(norm,1e-12) > 0.35, out[i] = sum_j kept_e * x[j].
// UNCHANGED from passing version (bit-identical output).
// -----------------------------------------------------------------------------
__global__ __launch_bounds__(256) void edge_out(
    const float* __restrict__ x, const float* __restrict__ u,
    const float* __restrict__ v, float* __restrict__ out)
{
    const size_t p = ((size_t)blockIdx.x * blockDim.x + threadIdx.x) * 4;
    if (p >= (size_t)PT) return;

    float xa[NIMG][4], ua[NIMG][4], va[NIMG][4];
    #pragma unroll
    for (int n2 = 0; n2 < NIMG; ++n2) {
        const float4 xv = *reinterpret_cast<const float4*>(&x[(size_t)n2 * PT + p]);
        const float4 uv = *reinterpret_cast<const float4*>(&u[(size_t)n2 * PT + p]);
        const float4 vv = *reinterpret_cast<const float4*>(&v[(size_t)n2 * PT + p]);
        xa[n2][0] = xv.x; xa[n2][1] = xv.y; xa[n2][2] = xv.z; xa[n2][3] = xv.w;
        ua[n2][0] = uv.x; ua[n2][1] = uv.y; ua[n2][2] = uv.z; ua[n2][3] = uv.w;
        va[n2][0] = vv.x; va[n2][1] = vv.y; va[n2][2] = vv.z; va[n2][3] = vv.w;
    }

    float oacc[NIMG][4];
    #pragma unroll
    for (int c = 0; c < 4; ++c) {
        #pragma unroll
        for (int i = 0; i < NIMG; ++i) {
            float e[NIMG];
            float sumsq = 0.0f;
            #pragma unroll
            for (int j = 0; j < NIMG; ++j) {
                e[j] = fabsf(ua[j][c] - va[i][c]);
                sumsq = fmaf(e[j], e[j], sumsq);
            }
            const float m = fmaxf(sqrtf(sumsq), 1e-12f);
            float h = 0.0f;
            #pragma unroll
            for (int j = 0; j < NIMG; ++j) {
                const float en = e[j] / m;
                if (en > 0.35f) h = fmaf(e[j], xa[j][c], h);
            }
            oacc[i][c] = h;
        }
    }

    #pragma unroll
    for (int i = 0; i < NIMG; ++i) {
        float4 ov = {oacc[i][0], oacc[i][1], oacc[i][2], oacc[i][3]};
        *reinterpret_cast<float4*>(&out[(size_t)i * PT + p]) = ov;
    }
}

extern "C" void kernel_launch(void* const* d_in, const int* in_sizes, int n_in,
                              void* d_out, int out_size, void* d_ws, size_t ws_size,
                              hipStream_t stream) {
    const float* x    = (const float*)d_in[0];
    const float* w    = (const float*)d_in[1];
    const float* bias = (const float*)d_in[2];
    float* out = (float*)d_out;

    float* u = (float*)d_ws;                       // 20 MB
    float* v = u + (size_t)NIMG * PT;              // 20 MB

    dim3 g1(HWP / BP, CCH / BD, NIMG);             // 64 x 4 x 5 = 1280 blocks
    uv_gemm<<<g1, 256, 0, stream>>>(x, w, bias, u, v);

    const int n4 = PT / 4;                         // 262144 float4 pixels
    edge_out<<<(n4 + 255) / 256, 256, 0, stream>>>(x, u, v, out);
}

// Round 4
// 87.181 us; speedup vs baseline: 1.1435x; 1.1435x over previous
//
#include <hip/hip_runtime.h>
#include <math.h>

// Problem constants (x: (5,1,256,64,64) f32)
constexpr int NIMG = 5;
constexpr int CCH  = 256;   // channels (both c and d)
constexpr int HWP  = 4096;  // H*W
constexpr int PT   = CCH * HWP;  // elems per image = 1048576

// Tiling: 32 d x 64 p per block, K-step 32, n-loop inside block.
constexpr int BD = 32;
constexpr int BP = 64;
constexpr int BK = 32;

// Async global->LDS, 16B/lane. LDS dest is wave-uniform base; HW adds lane*16.
__device__ __forceinline__ void gload16(const float* g, float* l) {
    __builtin_amdgcn_global_load_lds(
        (const __attribute__((address_space(1))) unsigned int*)g,
        (__attribute__((address_space(3))) unsigned int*)l, 16, 0, 0);
}

// -----------------------------------------------------------------------------
// Fully fused kernel. Per block: (d0,p0) tile, all 5 images.
//   acc_s[n] = sum_c x[n,c,p]*(W1+W2)[c,d]   (wsa = w1+w2 per cc: same fp32
//   acc_2[n] = sum_c x[n,c,p]*W2[c,d]         chain as passing versions)
// Epilogue (in-register, no u/v traffic):
//   u[n] = x[n] - acc_s[n] - b ;  v[n] = acc_2[n]
//   e[i][j] = |u[j]-v[i]| ; norm_i = sqrt(sum_j e^2)
//   out[i] = sum_j (e[i][j]/max(norm,1e-12) > 0.35 ? e[i][j]*x[j] : 0)
// Math ops/order copied verbatim from the passing edge_out -> bit-identical.
// -----------------------------------------------------------------------------
__global__ __launch_bounds__(256, 2) void fused_all(
    const float* __restrict__ x, const float* __restrict__ w,
    const float* __restrict__ bias, float* __restrict__ out)
{
    const int t  = threadIdx.x;
    const int tp = t & 15;   // p-frag: cols tp*4..+3
    const int td = t >> 4;   // d-frag: rows td*2, td*2+1
    const int p0 = blockIdx.x * BP;
    const int d0 = blockIdx.y * BD;

    __shared__ float xs [NIMG][BK][BP];  // 40 KB
    __shared__ float w1s[BK][BD];        // 4 KB
    __shared__ float w2s[BK][BD];        // 4 KB

    float acc_s[NIMG][2][4] = {};  // sum_c x*(W1+W2)
    float acc_2[NIMG][2][4] = {};  // sum_c x*W2

    const int wv = t >> 6, l = t & 63;
    const int xsr = l >> 4, xsc = (l & 15) * 4;  // x stage: 1KB chunk = 4 rows x 64
    const int wsr = l >> 3, wsc = (l & 7) * 4;   // w stage: 1KB chunk = 8 rows x 32

    for (int c0 = 0; c0 < CCH; c0 += BK) {
        // stage x: 5 tiles of [32][64] (8KB each = 8 wave-chunks; wave wv does 2)
        #pragma unroll
        for (int n = 0; n < NIMG; ++n) {
            #pragma unroll
            for (int k = 0; k < 2; ++k) {
                const int ch = wv + k * 4;         // chunk 0..7
                const int r  = ch * 4 + xsr;
                gload16(&x[(size_t)n * PT + (size_t)(c0 + r) * HWP + p0 + xsc],
                        &xs[n][ch * 4][0]);
            }
        }
        // stage w1,w2: [32][32] tiles (4KB = 4 wave-chunks; wave wv does chunk wv)
        {
            const int r = wv * 8 + wsr;
            gload16(&w[(size_t)(c0 + r) * CCH + d0 + wsc],       &w1s[wv * 8][0]);
            gload16(&w[(size_t)(256 + c0 + r) * CCH + d0 + wsc], &w2s[wv * 8][0]);
        }
        __syncthreads();

        #pragma unroll 8
        for (int cc = 0; cc < BK; ++cc) {
            const float2 w1v = *reinterpret_cast<const float2*>(&w1s[cc][td * 2]);
            const float2 w2v = *reinterpret_cast<const float2*>(&w2s[cc][td * 2]);
            const float w2a[2] = {w2v.x, w2v.y};
            const float wsa[2] = {w1v.x + w2v.x, w1v.y + w2v.y};
            #pragma unroll
            for (int n = 0; n < NIMG; ++n) {
                const float4 xv = *reinterpret_cast<const float4*>(&xs[n][cc][tp * 4]);
                const float xa[4] = {xv.x, xv.y, xv.z, xv.w};
                #pragma unroll
                for (int i = 0; i < 2; ++i) {
                    #pragma unroll
                    for (int j = 0; j < 4; ++j) {
                        acc_s[n][i][j] = fmaf(wsa[i], xa[j], acc_s[n][i][j]);
                        acc_2[n][i][j] = fmaf(w2a[i], xa[j], acc_2[n][i][j]);
                    }
                }
            }
        }
        __syncthreads();
    }

    // ---------------- fused epilogue: edges + threshold + reduce ----------------
    #pragma unroll
    for (int r = 0; r < 2; ++r) {
        const int d = d0 + td * 2 + r;
        const float bd = bias[d];
        const size_t base = (size_t)d * HWP + p0 + tp * 4;

        float xa[NIMG][4], ua[NIMG][4], va[NIMG][4];
        #pragma unroll
        for (int n = 0; n < NIMG; ++n) {
            const float4 xv = *reinterpret_cast<const float4*>(&x[(size_t)n * PT + base]);
            const float xt[4] = {xv.x, xv.y, xv.z, xv.w};
            #pragma unroll
            for (int q = 0; q < 4; ++q) {
                xa[n][q] = xt[q];
                ua[n][q] = xt[q] - acc_s[n][r][q] - bd;  // same order as before
                va[n][q] = acc_2[n][r][q];
            }
        }

        #pragma unroll
        for (int i = 0; i < NIMG; ++i) {
            float ho[4];
            #pragma unroll
            for (int q = 0; q < 4; ++q) {
                float e[NIMG];
                float sumsq = 0.0f;
                #pragma unroll
                for (int j = 0; j < NIMG; ++j) {
                    e[j] = fabsf(ua[j][q] - va[i][q]);
                    sumsq = fmaf(e[j], e[j], sumsq);
                }
                const float m = fmaxf(sqrtf(sumsq), 1e-12f);
                float h = 0.0f;
                #pragma unroll
                for (int j = 0; j < NIMG; ++j) {
                    const float en = e[j] / m;
                    if (en > 0.35f) h = fmaf(e[j], xa[j][q], h);
                }
                ho[q] = h;
            }
            const float4 ov = {ho[0], ho[1], ho[2], ho[3]};
            *reinterpret_cast<float4*>(&out[(size_t)i * PT + base]) = ov;
        }
    }
}

extern "C" void kernel_launch(void* const* d_in, const int* in_sizes, int n_in,
                              void* d_out, int out_size, void* d_ws, size_t ws_size,
                              hipStream_t stream) {
    const float* x    = (const float*)d_in[0];
    const float* w    = (const float*)d_in[1];
    const float* bias = (const float*)d_in[2];
    float* out = (float*)d_out;

    dim3 g(HWP / BP, CCH / BD);   // 64 x 8 = 512 blocks, 2 per CU
    fused_all<<<g, 256, 0, stream>>>(x, w, bias, out);
}

// Round 5
// 82.830 us; speedup vs baseline: 1.2036x; 1.0525x over previous
//
#include <hip/hip_runtime.h>
#include <math.h>

// Problem constants (x: (5,1,256,64,64) f32)
constexpr int NIMG = 5;
constexpr int CCH  = 256;   // channels (both c and d)
constexpr int HWP  = 4096;  // H*W
constexpr int PT   = CCH * HWP;  // elems per image = 1048576

// Tiling: 32 d x 64 p per block, K-step 16, double-buffered, n-loop in block.
constexpr int BD = 32;
constexpr int BP = 64;
constexpr int BK = 16;
constexpr int NSTEP = CCH / BK;   // 16

// Async global->LDS, 16B/lane. LDS dest is wave-uniform base; HW adds lane*16.
__device__ __forceinline__ void gload16(const float* g, float* l) {
    __builtin_amdgcn_global_load_lds(
        (const __attribute__((address_space(1))) unsigned int*)g,
        (__attribute__((address_space(3))) unsigned int*)l, 16, 0, 0);
}

// -----------------------------------------------------------------------------
// Fully fused: per block (d0,p0), all 5 images; 2-phase double-buffered K-loop
// with counted vmcnt (loads in flight across barriers — no vmcnt(0) drain
// mid-loop). Math chain identical to passing R4 version -> bit-identical out.
//   acc_s[n] = sum_c x[n,c,p]*(W1+W2)[c,d],  acc_2[n] = sum_c x[n,c,p]*W2[c,d]
//   u = x - acc_s - b ; v = acc_2 ; e=|u[j]-v[i]| ; thresholded weighted sum.
// -----------------------------------------------------------------------------
__global__ __launch_bounds__(256, 2) void fused_all(
    const float* __restrict__ x, const float* __restrict__ w,
    const float* __restrict__ bias, float* __restrict__ out)
{
    const int t  = threadIdx.x;
    const int tp = t & 15;   // p-frag: cols tp*4..+3
    const int td = t >> 4;   // d-frag: rows td*2, td*2+1
    const int p0 = blockIdx.x * BP;
    const int d0 = blockIdx.y * BD;

    __shared__ float xs [2][NIMG][BK][BP];  // 2 x 20 KB
    __shared__ float w1s[2][BK][BD];        // 2 x 2 KB
    __shared__ float w2s[2][BK][BD];        // 2 x 2 KB

    float acc_s[NIMG][2][4] = {};
    float acc_2[NIMG][2][4] = {};

    const int wv = t >> 6, l = t & 63;
    const int xr = l >> 4, xc = (l & 15) * 4;  // x chunk: 4 rows x 64 floats
    const int wr = l >> 3, wc = (l & 7) * 4;   // w chunk: 8 rows x 32 floats

    // Stage one K-step (c0) into buffer b. 6 gload16 per wave, uniform:
    //  - 5 x-chunks: global chunk id g = wv + 4s, s=0..4 -> n=g>>2, k=g&3
    //  - 1 w-chunk : wv<2 -> w1 chunk wv ; else w2 chunk wv-2
    auto stage = [&](int b, int c0) {
        #pragma unroll
        for (int s = 0; s < NIMG; ++s) {
            const int g = wv + 4 * s;
            const int n = g >> 2, k = g & 3;
            gload16(&x[(size_t)n * PT + (size_t)(c0 + k * 4 + xr) * HWP + p0 + xc],
                    &xs[b][n][k * 4][0]);
        }
        if (wv < 2) {
            gload16(&w[(size_t)(c0 + wv * 8 + wr) * CCH + d0 + wc],
                    &w1s[b][wv * 8][0]);
        } else {
            gload16(&w[(size_t)(256 + c0 + (wv - 2) * 8 + wr) * CCH + d0 + wc],
                    &w2s[b][(wv - 2) * 8][0]);
        }
    };

    stage(0, 0);

    for (int st = 0; st < NSTEP; ++st) {
        const int cur = st & 1;
        if (st + 1 < NSTEP) {
            stage(cur ^ 1, (st + 1) * BK);
            asm volatile("s_waitcnt vmcnt(6)" ::: "memory");  // step st's loads done
        } else {
            asm volatile("s_waitcnt vmcnt(0)" ::: "memory");
        }
        __builtin_amdgcn_s_barrier();   // buffer cur fully staged (all waves)

        #pragma unroll
        for (int cc = 0; cc < BK; ++cc) {
            const float2 w1v = *reinterpret_cast<const float2*>(&w1s[cur][cc][td * 2]);
            const float2 w2v = *reinterpret_cast<const float2*>(&w2s[cur][cc][td * 2]);
            const float w2a[2] = {w2v.x, w2v.y};
            const float wsa[2] = {w1v.x + w2v.x, w1v.y + w2v.y};
            #pragma unroll
            for (int n = 0; n < NIMG; ++n) {
                const float4 xv = *reinterpret_cast<const float4*>(&xs[cur][n][cc][tp * 4]);
                const float xa[4] = {xv.x, xv.y, xv.z, xv.w};
                #pragma unroll
                for (int i = 0; i < 2; ++i) {
                    #pragma unroll
                    for (int j = 0; j < 4; ++j) {
                        acc_s[n][i][j] = fmaf(wsa[i], xa[j], acc_s[n][i][j]);
                        acc_2[n][i][j] = fmaf(w2a[i], xa[j], acc_2[n][i][j]);
                    }
                }
            }
        }
        __builtin_amdgcn_s_barrier();   // compute done before next re-stage of cur^1
    }

    // ---------------- fused epilogue: edges + threshold + reduce ----------------
    #pragma unroll
    for (int r = 0; r < 2; ++r) {
        const int d = d0 + td * 2 + r;
        const float bd = bias[d];
        const size_t base = (size_t)d * HWP + p0 + tp * 4;

        float xa[NIMG][4], ua[NIMG][4], va[NIMG][4];
        #pragma unroll
        for (int n = 0; n < NIMG; ++n) {
            const float4 xv = *reinterpret_cast<const float4*>(&x[(size_t)n * PT + base]);
            const float xt[4] = {xv.x, xv.y, xv.z, xv.w};
            #pragma unroll
            for (int q = 0; q < 4; ++q) {
                xa[n][q] = xt[q];
                ua[n][q] = xt[q] - acc_s[n][r][q] - bd;
                va[n][q] = acc_2[n][r][q];
            }
        }

        #pragma unroll
        for (int i = 0; i < NIMG; ++i) {
            float ho[4];
            #pragma unroll
            for (int q = 0; q < 4; ++q) {
                float e[NIMG];
                float sumsq = 0.0f;
                #pragma unroll
                for (int j = 0; j < NIMG; ++j) {
                    e[j] = fabsf(ua[j][q] - va[i][q]);
                    sumsq = fmaf(e[j], e[j], sumsq);
                }
                const float m = fmaxf(sqrtf(sumsq), 1e-12f);
                float h = 0.0f;
                #pragma unroll
                for (int j = 0; j < NIMG; ++j) {
                    const float en = e[j] / m;
                    if (en > 0.35f) h = fmaf(e[j], xa[j][q], h);
                }
                ho[q] = h;
            }
            const float4 ov = {ho[0], ho[1], ho[2], ho[3]};
            *reinterpret_cast<float4*>(&out[(size_t)i * PT + base]) = ov;
        }
    }
}

extern "C" void kernel_launch(void* const* d_in, const int* in_sizes, int n_in,
                              void* d_out, int out_size, void* d_ws, size_t ws_size,
                              hipStream_t stream) {
    const float* x    = (const float*)d_in[0];
    const float* w    = (const float*)d_in[1];
    const float* bias = (const float*)d_in[2];
    float* out = (float*)d_out;

    dim3 g(HWP / BP, CCH / BD);   // 64 x 8 = 512 blocks
    fused_all<<<g, 256, 0, stream>>>(x, w, bias, out);
}